// Round 5
// baseline (1546.825 us; speedup 1.0000x reference)
//
#include <hip/hip_runtime.h>

// 8 independent LSTMs (HID=512, input=1 scalar/step) x T=256, batch 128, then a
// tiny (B,T)->(B,8) projection.
//
// Round 14: two independent wave-teams per CU (8 waves) to hide sync latency.
//  r13 post-mortem (WIN 1492->1292): per-wave closed groups engaged pure path
//  (FETCH 23MB = L2-local h). WRITE 312MB ~= poll-atomic count x 64B => TCC
//  atomics generate EA traffic => publish->detect is MALL-latency class. With
//  only 4 waves/CU (Occ 11.6%) that latency is fully exposed (~60% stall).
//  r14: 128 blocks x 512 threads (8 waves, still 1 block/CU). Block = 32 cols
//  (jt 0..15) x 128 rows; team 0 (w0-3) owns rows 0-63, team 1 (w4-7) rows
//  64-127. Teams have disjoint closed sync groups (16 waves across the 16
//  same-branch blocks) -> teams never wait on each other; SIMD pairs (w, w+4)
//  one wave per team -> poll stall of one team overlaps MFMA of the other.
//  Invariants kept from r13: branch n -> XCD n (128 blocks, i%8), 2MB/XCD/step
//  h traffic, 128 flag slots/XCD, frag-major conflict-free Wlds, per-wave
//  atomic flag protocol (publish L2+sc1 escrow, poll sc0 -> sc0sc1 escalate).
//  Impure fallback: same sync graph with sc0 sc1 (MALL) scope everywhere.

#define NBR   8
#define BATCH 128
#define HIDN  512
#define TLEN  256

typedef __attribute__((ext_vector_type(8))) short bf16x8;
typedef __attribute__((ext_vector_type(4))) float f32x4;

__device__ __forceinline__ unsigned short bf16_rne(float f) {
  unsigned int u = __float_as_uint(f);
  u += 0x7FFFu + ((u >> 16) & 1u);
  return (unsigned short)(u >> 16);
}

__device__ __forceinline__ float sigm(float x) {
  return __builtin_amdgcn_rcpf(1.0f + __expf(-x));
}
__device__ __forceinline__ float tanh_(float x) {
  float ax = fabsf(x);
  float e  = __expf(-2.0f * ax);
  float t  = (1.0f - e) * __builtin_amdgcn_rcpf(1.0f + e);
  return copysignf(t, x);
}

#define HLOADX(d, p, OFF, SC) \
  asm volatile("global_load_dwordx4 %0, %1, off offset:" OFF " " SC \
               : "=v"(d) : "v"(p))
#define DLOADX(d, p, SC) \
  asm volatile("global_load_dword %0, %1, off " SC : "=v"(d) : "v"(p))
#define DLOADF(d, p, SC) \
  asm volatile("global_load_dword %0, %1, off " SC : "=v"(d) : "v"(p))
#define QSTOREX(p, v, SC) \
  asm volatile("global_store_dwordx2 %0, %1, off " SC \
               :: "v"(p), "v"(v) : "memory")
#define QSTOREXO(p, v, OFF, SC) \
  asm volatile("global_store_dwordx2 %0, %1, off offset:" OFF " " SC \
               :: "v"(p), "v"(v) : "memory")
#define DSTOREX(p, v, SC) \
  asm volatile("global_store_dword %0, %1, off " SC \
               :: "v"(p), "v"(v) : "memory")
#define WAITV(N) asm volatile("s_waitcnt vmcnt(" #N ")" ::: "memory")
#define INVL1() asm volatile("buffer_inv sc0" ::: "memory")
#define SCHEDB() __builtin_amdgcn_sched_barrier(0)
#define AUMAX_NR(p, v, SC) \
  asm volatile("global_atomic_umax %0, %1, off " SC :: "v"(p), "v"(v) : "memory")
#define AUMAX_RET(d, p, v, SC) \
  asm volatile("global_atomic_umax %0, %1, %2, off " SC \
               : "=v"(d) : "v"(p), "v"(v) : "memory")

// 16 x 16B: row bb, bytes [q*16 + j*64], j = 0..15 (4 chunks of 4 ksteps).
#define LOAD_H(SC) do {                         \
    HLOADX(hvv[0][0], pc, "0",   SC);           \
    HLOADX(hvv[0][1], pc, "64",  SC);           \
    HLOADX(hvv[0][2], pc, "128", SC);           \
    HLOADX(hvv[0][3], pc, "192", SC);           \
    HLOADX(hvv[1][0], pc, "256", SC);           \
    HLOADX(hvv[1][1], pc, "320", SC);           \
    HLOADX(hvv[1][2], pc, "384", SC);           \
    HLOADX(hvv[1][3], pc, "448", SC);           \
    HLOADX(hvv[2][0], pc, "512", SC);           \
    HLOADX(hvv[2][1], pc, "576", SC);           \
    HLOADX(hvv[2][2], pc, "640", SC);           \
    HLOADX(hvv[2][3], pc, "704", SC);           \
    HLOADX(hvv[3][0], pc, "768", SC);           \
    HLOADX(hvv[3][1], pc, "832", SC);           \
    HLOADX(hvv[3][2], pc, "896", SC);           \
    HLOADX(hvv[3][3], pc, "960", SC);           \
  } while (0)

// 8 tiles tt = gate*2 + u; W from frag-major LDS (64 consecutive uint4 per
// read -> conflict-free).
#define MFMA_CHUNK(C) do {                                                    \
    _Pragma("unroll")                                                         \
    for (int k4 = 0; k4 < 4; ++k4) {                                          \
      bf16x8 hfrag = __builtin_bit_cast(bf16x8, hvv[C][k4]);                  \
      _Pragma("unroll")                                                       \
      for (int tt = 0; tt < 8; ++tt) {                                        \
        bf16x8 wf = __builtin_bit_cast(bf16x8,                                \
            Wlds[tt * 1024 + (4 * (C) + k4) * 64 + wb]);                      \
        acc[tt] = __builtin_amdgcn_mfma_f32_16x16x32_bf16(                    \
            wf, hfrag, acc[tt], 0, 0, 0);                                     \
      }                                                                       \
    }                                                                         \
  } while (0)

// FM==1: pure (plain h exchange in local L2, per-wave atomic flags).
// FM==0: fallback, same sync graph at MALL scope (sc0 sc1).
#define STEP_LOOP(SC, FM)                                                     \
  for (int t = 0; t < TLEN; ++t) {                                            \
    f32x4 acc[8];                                                             \
    _Pragma("unroll")                                                         \
    for (int tt = 0; tt < 8; ++tt) acc[tt] = (f32x4){0.f, 0.f, 0.f, 0.f};     \
    const char* pc = curB + hoff;                                             \
    uint4 hvv[4][4];                                                          \
    float cv;                                                                 \
    DLOADF(cv, c_ptr + t, "");                                                \
    LOAD_H(SC);                                                               \
    WAITV(12); SCHEDB(); MFMA_CHUNK(0);                                       \
    WAITV(8);  SCHEDB(); MFMA_CHUNK(1);                                       \
    WAITV(4);  SCHEDB(); MFMA_CHUNK(2);                                       \
    WAITV(0);  SCHEDB(); MFMA_CHUNK(3);                                       \
    _Pragma("unroll")                                                         \
    for (int u = 0; u < 2; ++u) {                                             \
      unsigned lo = 0, hi = 0;                                                \
      _Pragma("unroll")                                                       \
      for (int r = 0; r < 4; ++r) {                                           \
        float2 pI = Bp[ 0 + u * 16 + q4 + r];                                 \
        float2 pF = Bp[32 + u * 16 + q4 + r];                                 \
        float2 pG = Bp[64 + u * 16 + q4 + r];                                 \
        float2 pO = Bp[96 + u * 16 + q4 + r];                                 \
        float gi = acc[0 + u][r] + pI.x * cv + pI.y;                          \
        float gf = acc[2 + u][r] + pF.x * cv + pF.y;                          \
        float gg = acc[4 + u][r] + pG.x * cv + pG.y;                          \
        float go = acc[6 + u][r] + pO.x * cv + pO.y;                          \
        float ncc = sigm(gf) * cc[u][r] + sigm(gi) * tanh_(gg);               \
        cc[u][r] = ncc;                                                       \
        float hval = sigm(go) * tanh_(ncc);                                   \
        unsigned hb = bf16_rne(hval);                                         \
        if (r == 0) lo = hb;                                                  \
        if (r == 1) lo |= hb << 16;                                           \
        if (r == 2) hi = hb;                                                  \
        if (r == 3) hi |= hb << 16;                                           \
        if (u == 1 && r == 3 && jt == 15 && q == 3)                           \
          ys[t * (NBR * BATCH) + n * BATCH + bb] = hval;                      \
      }                                                                       \
      unsigned long long pack =                                               \
          (unsigned long long)lo | ((unsigned long long)hi << 32);            \
      QSTOREX(nxtB + (u ? soff1 : soff0), pack, SC);                          \
    }                                                                         \
    if (t == TLEN - 1) break;                                                 \
    WAITV(0);                      /* my stores L2-acked */                   \
    const unsigned tgt = (unsigned)(t + 1);                                   \
    if (FM) {                                                                 \
      if (lane == 0) { AUMAX_NR(myflag, tgt, "");                             \
                       AUMAX_NR(myflag, tgt, "sc1"); }                        \
      int spins = 0;                                                          \
      for (;;) {                                                              \
        unsigned fv = 0xFFFFFFFFu;                                            \
        if (lane < 16) {                                                      \
          if (spins < 256) { AUMAX_RET(fv, ppoll, 0u, "sc0"); }               \
          else             { AUMAX_RET(fv, ppoll, 0u, "sc0 sc1"); }           \
        }                                                                     \
        WAITV(0); SCHEDB();                                                   \
        if (__all((int)(fv >= tgt))) break;                                   \
        ++spins; __builtin_amdgcn_s_sleep(1);                                 \
      }                                                                       \
      INVL1(); WAITV(0);           /* L1 clean BEFORE next step's h loads */  \
    } else {                                                                  \
      if (lane == 0) DSTOREX(myflag, tgt, "sc0 sc1");                         \
      for (;;) {                                                              \
        unsigned f0v;                                                         \
        DLOADX(f0v, ipoll, "sc0 sc1");                                        \
        WAITV(0); SCHEDB();                                                   \
        if (__all((int)(f0v >= tgt))) break;                                  \
        __builtin_amdgcn_s_sleep(1);                                          \
      }                                                                       \
    }                                                                         \
    char* tsw = curB; curB = nxtB; nxtB = tsw;                                \
  }

__global__ __launch_bounds__(512, 1) void lstm_main(
    const float* __restrict__ c_in,   // (128,256)
    const float* __restrict__ Wih,    // (8,2048)
    const float* __restrict__ Whh,    // (8,2048,512)
    const float* __restrict__ b_ih,   // (8,2048)
    const float* __restrict__ b_hh,   // (8,2048)
    char* __restrict__ hImp,          // 2MB impure ping+pong, pre-zeroed ping
    char* __restrict__ hPure,         // 2MB: 8 XCD regions x (128KB ping + 128KB pong)
    float* __restrict__ ys,           // (256,8,128)
    unsigned int* __restrict__ iflags,// 8x128 impure per-wave flags, pre-zeroed
    unsigned int* __restrict__ pflags,// 8 XCD x 128 wave-slots x 16 u32 (64B pads)
    unsigned int* __restrict__ vx,    // 128 tagged XCC slots, pre-zeroed
    unsigned int* __restrict__ vdict, // 8 verdicts, pre-zeroed
    unsigned int* __restrict__ ibar)  // 8x32 init-barrier slots, pre-zeroed
{
  // Frag-major W: slot = tile*1024 + ks*64 + q*16 + ln15  (tile = gate*2 + u).
  __shared__ uint4 Wlds[8192];  // 128KB
  __shared__ float2 Bp[128];    // {Wih, b_ih+b_hh} per slice gate-row

  const int tid  = threadIdx.x;
  const int lane = tid & 63;
  const int w    = tid >> 6;          // 0..7
  const int ln15 = lane & 15;
  const int q    = lane >> 4;
  const int q4   = q * 4;
  const int n    = blockIdx.x & 7;    // branch
  const int jt   = blockIdx.x >> 3;   // 0..15 hidden-col tile (32 cols)
  const int j0   = jt << 5;
  const int team = w >> 2;            // 0: rows 0-63, 1: rows 64-127
  const int wsub = w & 3;
  const int wb   = q * 16 + ln15;     // frag-major LDS read base (uint4)

  unsigned xcc_raw;
  asm volatile("s_getreg_b32 %0, hwreg(HW_REG_XCC_ID)" : "=s"(xcc_raw));
  const unsigned xcc = xcc_raw & 0xFu;
  if (tid == 0) DSTOREX(&vx[blockIdx.x], 0xA5000000u | xcc, "sc0 sc1");

  // ---- stage Whh slice -> LDS bf16, frag-major, dest-linear (once) ----
  for (int idx = tid; idx < 8192; idx += 512) {
    int ln   = idx & 15;          // wcol within 16-col tile
    int q_   = (idx >> 4) & 3;    // k quarter (8 floats)
    int ks_  = (idx >> 6) & 15;   // kstep (32 floats)
    int tile = idx >> 10;         // 0..7 = gate*2 + u
    int g_   = tile >> 1;
    int uu   = tile & 1;
    const float* src = Whh +
        (size_t)(n * 2048 + g_ * 512 + j0 + uu * 16 + ln) * 512 + ks_ * 32 + q_ * 8;
    float4 f0 = *(const float4*)(src);
    float4 f1 = *(const float4*)(src + 4);
    uint4 v;
    v.x = (unsigned)bf16_rne(f0.x) | ((unsigned)bf16_rne(f0.y) << 16);
    v.y = (unsigned)bf16_rne(f0.z) | ((unsigned)bf16_rne(f0.w) << 16);
    v.z = (unsigned)bf16_rne(f1.x) | ((unsigned)bf16_rne(f1.y) << 16);
    v.w = (unsigned)bf16_rne(f1.z) | ((unsigned)bf16_rne(f1.w) << 16);
    Wlds[idx] = v;
  }
  if (tid < 128) {
    int g = n * 2048 + (tid >> 5) * 512 + j0 + (tid & 31);
    Bp[tid] = make_float2(Wih[g], b_ih[g] + b_hh[g]);
  }

  // ---- leader (jt==0, wave 0): bounded purity check, publish verdict ----
  if (jt == 0 && w == 0) {
    const unsigned ref = 0xA5000000u | xcc;
    unsigned v0 = 0, v1 = 0;
    int ok = 0;
    for (int it = 0; it < 16384; ++it) {
      DLOADX(v0, &vx[lane],      "sc0 sc1");
      DLOADX(v1, &vx[lane + 64], "sc0 sc1");
      WAITV(0);
      if (__all((int)(((v0 & 0xFF000000u) == 0xA5000000u) &&
                      ((v1 & 0xFF000000u) == 0xA5000000u)))) { ok = 1; break; }
      __builtin_amdgcn_s_sleep(1);
    }
    unsigned verdict = 0;
    if (ok) {
      const bool mine = ((lane & 7) == n);
      int uni = __all((int)(!mine || (v0 == ref && v1 == ref)));
      int oth = __all((int)( mine || (v0 != ref && v1 != ref)));
      verdict = (uni && oth && (xcc < 8u)) ? 1u : 0u;
    }
    if (lane == 0)
      DSTOREX(&vdict[n], 0xB5000000u | (verdict << 8) | xcc, "sc0 sc1");
  }

  unsigned vd;
  for (;;) {
    DLOADX(vd, &vdict[n], "sc0 sc1");
    WAITV(0);
    if ((vd & 0xFF000000u) == 0xB5000000u) break;
    __builtin_amdgcn_s_sleep(2);
  }
  const int pure   = (int)((vd >> 8) & 1u);
  const unsigned x = vd & 0xFu;

  const int bb = team * 64 + wsub * 16 + ln15;  // my batch row (0..127)
  const size_t hoff  = (size_t)bb * 1024 + (size_t)q * 16;
  const size_t soff0 = (size_t)bb * 1024 + (size_t)(j0 + q4) * 2;
  const size_t soff1 = soff0 + 32;              // +16 cols
  const float* c_ptr = c_in + (size_t)bb * 256;

  float cc[2][4];
#pragma unroll
  for (int u = 0; u < 2; ++u)
#pragma unroll
    for (int r = 0; r < 4; ++r) cc[u][r] = 0.0f;

  // Sync group: the 16 waves (same w, jt=0..15) of my branch — closed set.
  char *curB, *nxtB;
  unsigned int *myflag;
  const unsigned int *ppoll, *ipoll;
  if (pure) {
    curB = hPure + (size_t)x * 262144; nxtB = curB + 131072;
    unsigned int* flagB = pflags + x * 2048;     // 128 slots x 16 u32
    myflag = flagB + (w * 16 + jt) * 16;
    ppoll  = flagB + (w * 16 + (lane & 15)) * 16;
    ipoll  = flagB;                              // unused
  } else {
    curB = hImp + (size_t)n * 131072; nxtB = curB + (size_t)NBR * 131072;
    unsigned int* flagB = iflags + n * 128;      // 128 plain u32
    myflag = flagB + w * 16 + jt;
    ipoll  = flagB + w * 16 + (lane & 15);       // one 64B line per group
    ppoll  = flagB;                              // unused
  }

  __syncthreads();   // Wlds + Bp ready; every wave has the verdict

  if (pure) {
    // scrub my 1/16 of region[x] to 0 (stale dirty lines live only in THIS L2)
    char* rp = hPure + (size_t)x * 262144 + (size_t)jt * 16384;
    for (int i = tid; i < 2048; i += 512)
      QSTOREXO(rp + (size_t)i * 8, 0ull, "0", "sc0");
    // scrub my wave's flag line: L2 first (dirty-0), THEN MALL (eviction-safe)
    if (lane == 0) {
      DSTOREX(myflag, 0u, "sc0");
      WAITV(0);
      DSTOREX(myflag, 0u, "sc0 sc1");
    }
    WAITV(0);
    __syncthreads();
    if (tid == 0) DSTOREX(&ibar[x * 32 + jt], 1u, "sc0 sc1");
    for (;;) {
      unsigned iv;
      DLOADX(iv, &ibar[x * 32 + (lane & 15)], "sc0 sc1");
      WAITV(0);
      if (__all((int)(iv >= 1u))) break;
      __builtin_amdgcn_s_sleep(2);
    }
    INVL1(); WAITV(0);
    STEP_LOOP("", 1)
  } else {
    STEP_LOOP("sc0 sc1", 0)
  }
}

// out[b,j] = sum_t (sum_n ys[t,n,b] * x[n,b,t]) * Wl[j,t] + bl[j]
__global__ __launch_bounds__(256) void finalize_k(
    const float* __restrict__ ys, const float* __restrict__ x,
    const float* __restrict__ Wl, const float* __restrict__ bl,
    float* __restrict__ out)
{
  int b = blockIdx.x;
  int tid = threadIdx.x;  // = t
  __shared__ float r[256];
  float acc = 0.f;
#pragma unroll
  for (int n = 0; n < NBR; ++n)
    acc += ys[tid * (NBR * BATCH) + n * BATCH + b] * x[(n * BATCH + b) * 256 + tid];
  r[tid] = acc;
  __syncthreads();
  int wv = tid >> 6, ln = tid & 63;
#pragma unroll
  for (int jj = 0; jj < 2; ++jj) {
    int j = wv * 2 + jj;
    float p = 0.f;
#pragma unroll
    for (int t2 = ln; t2 < 256; t2 += 64) p += r[t2] * Wl[j * 256 + t2];
#pragma unroll
    for (int s = 32; s > 0; s >>= 1) p += __shfl_down(p, s, 64);
    if (ln == 0) out[b * NBR + j] = p + bl[j];
  }
}

extern "C" void kernel_launch(void* const* d_in, const int* in_sizes, int n_in,
                              void* d_out, int out_size, void* d_ws, size_t ws_size,
                              hipStream_t stream) {
  const float* x    = (const float*)d_in[0];
  const float* c    = (const float*)d_in[1];
  const float* Wih  = (const float*)d_in[2];
  const float* Whh  = (const float*)d_in[3];
  const float* b_ih = (const float*)d_in[4];
  const float* b_hh = (const float*)d_in[5];
  // d_in[6] = hn0 (zeros; impure ping memset, pure regions scrubbed in-kernel)
  const float* Wl   = (const float*)d_in[7];
  const float* bl   = (const float*)d_in[8];
  float* out = (float*)d_out;

  char* ws = (char*)d_ws;
  char*  hImp  = ws;                                   // 2MB
  char*  hPure = ws + (2u << 20);                      // 2MB (8 x 256KB, XCD-indexed)
  float* ys    = (float*)(ws + (4u << 20));            // 1MB
  unsigned int* ctrl   = (unsigned int*)(ws + (5u << 20));
  unsigned int* iflags = ctrl;                         // 1024 u32
  unsigned int* pflags = ctrl + 1024;                  // 16384 u32 (8 x 128 x 16)
  unsigned int* vx     = ctrl + 17408;                 // 256 u32 (128 used)
  unsigned int* vdict  = ctrl + 17664;                 // 8 u32
  unsigned int* ibar   = ctrl + 17672;                 // 256 u32

  // ws re-poisoned (0xAA) before every timed launch: re-init every call.
  (void)hipMemsetAsync(hImp, 0, 1u << 20, stream);     // impure h(t=0) = 0
  (void)hipMemsetAsync(ctrl, 0, 17928u * sizeof(unsigned int), stream);

  lstm_main<<<128, 512, 0, stream>>>(c, Wih, Whh, b_ih, b_hh, hImp, hPure, ys,
                                     iflags, pflags, vx, vdict, ibar);
  finalize_k<<<BATCH, 256, 0, stream>>>(ys, x, Wl, bl, out);
}

// Round 6
// 1093.432 us; speedup vs baseline: 1.4147x; 1.4147x over previous
//
#include <hip/hip_runtime.h>

// 8 independent LSTMs (HID=512, input=1 scalar/step) x T=256, batch 128, then a
// tiny (B,T)->(B,8) projection.
//
// Round 15: r13 geometry + per-group COUNTER sync (1 atomic/poll-round).
//  r14 post-mortem (FAILED 1292->1547): 128 blocks x 8 waves halved active CUs
//  (Occ stayed 11.7% = same 1024 total waves); teams were in-phase, not
//  antiphase; per-CU compute doubled. Reverted.
//  r13 residual analysis: WRITE 312MB => ~150 poll-atomics/wave/step = 16
//  lanes x ~9 rounds; per XCD per round 1024 atomics hit the TCC atomic pipe
//  => detection is CONTENTION-bound, not skew-bound.
//  r15 changes vs r13 (geometry/W-layout/impure fallback identical):
//   - Per-group counters: the 16-wave group (bt,w, jt=0..15) shares ONE
//     counter. Producer lane0: atomic_add(+1) plain (L2) + atomic_add(+1) sc1
//     into a SEPARATE MALL-escrow counter (no double count). Consumer: lane0
//     polls umax(0) sc0 on the L2 counter until >= 16*(t+1); escalates to the
//     MALL counter (sc0 sc1) after 256 spins. 16x fewer poll atomics.
//   - INVL1 issued BEFORE the poll loop (atomics bypass L1; no L1 fill occurs
//     between inv and the post-detect h loads) - one less serial vmem op.
//  Counters are monotone (max 16*256 = 4096); scrubbed by the jt==0 blocks
//  (L2 dirty-0 first, then MALL escrow) before the ibar init-barrier.

#define NBR   8
#define BATCH 128
#define HIDN  512
#define TLEN  256

typedef __attribute__((ext_vector_type(8))) short bf16x8;
typedef __attribute__((ext_vector_type(4))) float f32x4;

__device__ __forceinline__ unsigned short bf16_rne(float f) {
  unsigned int u = __float_as_uint(f);
  u += 0x7FFFu + ((u >> 16) & 1u);
  return (unsigned short)(u >> 16);
}

__device__ __forceinline__ float sigm(float x) {
  return __builtin_amdgcn_rcpf(1.0f + __expf(-x));
}
__device__ __forceinline__ float tanh_(float x) {
  float ax = fabsf(x);
  float e  = __expf(-2.0f * ax);
  float t  = (1.0f - e) * __builtin_amdgcn_rcpf(1.0f + e);
  return copysignf(t, x);
}

#define HLOADX(d, p, OFF, SC) \
  asm volatile("global_load_dwordx4 %0, %1, off offset:" OFF " " SC \
               : "=v"(d) : "v"(p))
#define DLOADX(d, p, SC) \
  asm volatile("global_load_dword %0, %1, off " SC : "=v"(d) : "v"(p))
#define DLOADF(d, p, SC) \
  asm volatile("global_load_dword %0, %1, off " SC : "=v"(d) : "v"(p))
#define QSTOREX(p, v, SC) \
  asm volatile("global_store_dwordx2 %0, %1, off " SC \
               :: "v"(p), "v"(v) : "memory")
#define QSTOREXO(p, v, OFF, SC) \
  asm volatile("global_store_dwordx2 %0, %1, off offset:" OFF " " SC \
               :: "v"(p), "v"(v) : "memory")
#define DSTOREX(p, v, SC) \
  asm volatile("global_store_dword %0, %1, off " SC \
               :: "v"(p), "v"(v) : "memory")
#define WAITV(N) asm volatile("s_waitcnt vmcnt(" #N ")" ::: "memory")
#define INVL1() asm volatile("buffer_inv sc0" ::: "memory")
#define SCHEDB() __builtin_amdgcn_sched_barrier(0)
// L2-executed atomics: cannot be served stale by L1. sc0 on the RET form is
// required (return-old); plain NR form executes at L2, sc1 form at MALL.
#define AADD_NR(p, v, SC) \
  asm volatile("global_atomic_add %0, %1, off " SC :: "v"(p), "v"(v) : "memory")
#define AUMAX_RET(d, p, v, SC) \
  asm volatile("global_atomic_umax %0, %1, %2, off " SC \
               : "=v"(d) : "v"(p), "v"(v) : "memory")

// 16 x 16B: row bb, bytes [q*16 + j*64], j = 0..15 (4 chunks of 4 ksteps).
#define LOAD_H(SC) do {                         \
    HLOADX(hvv[0][0], pc, "0",   SC);           \
    HLOADX(hvv[0][1], pc, "64",  SC);           \
    HLOADX(hvv[0][2], pc, "128", SC);           \
    HLOADX(hvv[0][3], pc, "192", SC);           \
    HLOADX(hvv[1][0], pc, "256", SC);           \
    HLOADX(hvv[1][1], pc, "320", SC);           \
    HLOADX(hvv[1][2], pc, "384", SC);           \
    HLOADX(hvv[1][3], pc, "448", SC);           \
    HLOADX(hvv[2][0], pc, "512", SC);           \
    HLOADX(hvv[2][1], pc, "576", SC);           \
    HLOADX(hvv[2][2], pc, "640", SC);           \
    HLOADX(hvv[2][3], pc, "704", SC);           \
    HLOADX(hvv[3][0], pc, "768", SC);           \
    HLOADX(hvv[3][1], pc, "832", SC);           \
    HLOADX(hvv[3][2], pc, "896", SC);           \
    HLOADX(hvv[3][3], pc, "960", SC);           \
  } while (0)

// 8 tiles tt = gate*2 + u (u = col-16-half); acc[tt] over K chunks. W from
// frag-major LDS: index tt*1024 + ks*64 + wb (wb = q*16+ln15) -> each read is
// 64 consecutive uint4 = conflict-free.
#define MFMA_CHUNK(C) do {                                                    \
    _Pragma("unroll")                                                         \
    for (int k4 = 0; k4 < 4; ++k4) {                                          \
      bf16x8 hfrag = __builtin_bit_cast(bf16x8, hvv[C][k4]);                  \
      _Pragma("unroll")                                                       \
      for (int tt = 0; tt < 8; ++tt) {                                        \
        bf16x8 wf = __builtin_bit_cast(bf16x8,                                \
            Wlds[tt * 1024 + (4 * (C) + k4) * 64 + wb]);                      \
        acc[tt] = __builtin_amdgcn_mfma_f32_16x16x32_bf16(                    \
            wf, hfrag, acc[tt], 0, 0, 0);                                     \
      }                                                                       \
    }                                                                         \
  } while (0)

// FM==1: pure (plain h exchange in local L2, per-group counter sync).
// FM==0: r3-class MALL protocol (sc0 sc1 everywhere), per-wave flags.
#define STEP_LOOP(SC, FM)                                                     \
  for (int t = 0; t < TLEN; ++t) {                                            \
    f32x4 acc[8];                                                             \
    _Pragma("unroll")                                                         \
    for (int tt = 0; tt < 8; ++tt) acc[tt] = (f32x4){0.f, 0.f, 0.f, 0.f};     \
    const char* pc = curB + hoff;                                             \
    uint4 hvv[4][4];                                                          \
    float cv;                                                                 \
    DLOADF(cv, c_ptr + t, "");                                                \
    LOAD_H(SC);                                                               \
    WAITV(12); SCHEDB(); MFMA_CHUNK(0);                                       \
    WAITV(8);  SCHEDB(); MFMA_CHUNK(1);                                       \
    WAITV(4);  SCHEDB(); MFMA_CHUNK(2);                                       \
    WAITV(0);  SCHEDB(); MFMA_CHUNK(3);                                       \
    _Pragma("unroll")                                                         \
    for (int u = 0; u < 2; ++u) {                                             \
      unsigned lo = 0, hi = 0;                                                \
      _Pragma("unroll")                                                       \
      for (int r = 0; r < 4; ++r) {                                           \
        float2 pI = Bp[ 0 + u * 16 + q4 + r];                                 \
        float2 pF = Bp[32 + u * 16 + q4 + r];                                 \
        float2 pG = Bp[64 + u * 16 + q4 + r];                                 \
        float2 pO = Bp[96 + u * 16 + q4 + r];                                 \
        float gi = acc[0 + u][r] + pI.x * cv + pI.y;                          \
        float gf = acc[2 + u][r] + pF.x * cv + pF.y;                          \
        float gg = acc[4 + u][r] + pG.x * cv + pG.y;                          \
        float go = acc[6 + u][r] + pO.x * cv + pO.y;                          \
        float ncc = sigm(gf) * cc[u][r] + sigm(gi) * tanh_(gg);               \
        cc[u][r] = ncc;                                                       \
        float hval = sigm(go) * tanh_(ncc);                                   \
        unsigned hb = bf16_rne(hval);                                         \
        if (r == 0) lo = hb;                                                  \
        if (r == 1) lo |= hb << 16;                                           \
        if (r == 2) hi = hb;                                                  \
        if (r == 3) hi |= hb << 16;                                           \
        if (u == 1 && r == 3 && jt == 15 && q == 3)                           \
          ys[t * (NBR * BATCH) + n * BATCH + bb] = hval;                      \
      }                                                                       \
      unsigned long long pack =                                               \
          (unsigned long long)lo | ((unsigned long long)hi << 32);            \
      QSTOREX(nxtB + (u ? soff1 : soff0), pack, SC);                          \
    }                                                                         \
    if (t == TLEN - 1) break;                                                 \
    WAITV(0);                      /* my stores L2-acked */                   \
    const unsigned tgt = (unsigned)(t + 1);                                   \
    if (FM) {                                                                 \
      if (lane == 0) { AADD_NR(cnt2, one, "");                                \
                       AADD_NR(cntM, one, "sc1"); }                           \
      INVL1();                     /* L1 clean; atomics won't refill it */    \
      const unsigned tgt16 = tgt << 4;                                        \
      int spins = 0;                                                          \
      for (;;) {                                                              \
        unsigned fv = 0xFFFFFFFFu;                                            \
        if (lane == 0) {                                                      \
          if (spins < 256) { AUMAX_RET(fv, cnt2, 0u, "sc0"); }                \
          else             { AUMAX_RET(fv, cntM, 0u, "sc0 sc1"); }            \
        }                                                                     \
        WAITV(0); SCHEDB();        /* also drains the buffer_inv */           \
        if (__all((int)(fv >= tgt16))) break;                                 \
        ++spins; __builtin_amdgcn_s_sleep(1);                                 \
      }                                                                       \
    } else {                                                                  \
      if (lane == 0) DSTOREX(myflag, tgt, "sc0 sc1");                         \
      for (;;) {                                                              \
        unsigned f0v;                                                         \
        DLOADX(f0v, pf0, "sc0 sc1");                                          \
        WAITV(0); SCHEDB();                                                   \
        if (__all((int)(f0v >= tgt))) break;                                  \
        __builtin_amdgcn_s_sleep(1);                                          \
      }                                                                       \
    }                                                                         \
    char* tsw = curB; curB = nxtB; nxtB = tsw;                                \
  }

__global__ __launch_bounds__(256, 1) void lstm_main(
    const float* __restrict__ c_in,   // (128,256)
    const float* __restrict__ Wih,    // (8,2048)
    const float* __restrict__ Whh,    // (8,2048,512)
    const float* __restrict__ b_ih,   // (8,2048)
    const float* __restrict__ b_hh,   // (8,2048)
    char* __restrict__ hImp,          // 2MB impure ping+pong, pre-zeroed ping
    char* __restrict__ hPure,         // 2MB: 8 XCD regions x (128KB ping + 128KB pong)
    float* __restrict__ ys,           // (256,8,128)
    unsigned int* __restrict__ iflags,// 8x128 impure per-wave flags, pre-zeroed
    unsigned int* __restrict__ pcnt,  // 8 XCD x {8 L2-cnt, 8 MALL-cnt} x 16 u32
    unsigned int* __restrict__ vx,    // 256 tagged XCC slots, pre-zeroed
    unsigned int* __restrict__ vdict, // 8 verdicts, pre-zeroed
    unsigned int* __restrict__ ibar)  // 8x32 init-barrier slots, pre-zeroed
{
  // Frag-major W: slot = tile*1024 + ks*64 + q*16 + ln15  (tile = gate*2 + u).
  // Each ds_read_b128 (fixed tile,ks) touches 64 CONSECUTIVE uint4 slots.
  __shared__ uint4 Wlds[8192];  // 128KB
  __shared__ float2 Bp[128];    // {Wih, b_ih+b_hh} per slice gate-row

  const int tid  = threadIdx.x;
  const int lane = tid & 63;
  const int w    = tid >> 6;
  const int ln15 = lane & 15;
  const int q    = lane >> 4;
  const int q4   = q * 4;
  const int n    = blockIdx.x & 7;    // branch
  const int m    = blockIdx.x >> 3;   // 0..31
  const int jt   = m & 15;            // hidden-col tile (32 cols)
  const int bt   = m >> 4;            // batch half (64 rows)
  const int j0   = jt << 5;
  const int wb   = q * 16 + ln15;     // frag-major LDS read base (uint4)
  const unsigned one = 1u;

  unsigned xcc_raw;
  asm volatile("s_getreg_b32 %0, hwreg(HW_REG_XCC_ID)" : "=s"(xcc_raw));
  const unsigned xcc = xcc_raw & 0xFu;
  if (tid == 0) DSTOREX(&vx[blockIdx.x], 0xA5000000u | xcc, "sc0 sc1");

  // ---- stage Whh slice -> LDS bf16, frag-major, dest-linear (once) ----
  for (int idx = tid; idx < 8192; idx += 256) {
    int ln   = idx & 15;          // wcol within 16-col tile
    int q_   = (idx >> 4) & 3;    // k quarter (8 floats)
    int ks_  = (idx >> 6) & 15;   // kstep (32 floats)
    int tile = idx >> 10;         // 0..7 = gate*2 + u
    int g_   = tile >> 1;
    int uu   = tile & 1;
    const float* src = Whh +
        (size_t)(n * 2048 + g_ * 512 + j0 + uu * 16 + ln) * 512 + ks_ * 32 + q_ * 8;
    float4 f0 = *(const float4*)(src);
    float4 f1 = *(const float4*)(src + 4);
    uint4 v;
    v.x = (unsigned)bf16_rne(f0.x) | ((unsigned)bf16_rne(f0.y) << 16);
    v.y = (unsigned)bf16_rne(f0.z) | ((unsigned)bf16_rne(f0.w) << 16);
    v.z = (unsigned)bf16_rne(f1.x) | ((unsigned)bf16_rne(f1.y) << 16);
    v.w = (unsigned)bf16_rne(f1.z) | ((unsigned)bf16_rne(f1.w) << 16);
    Wlds[idx] = v;
  }
  if (tid < 128) {
    int g = n * 2048 + (tid >> 5) * 512 + j0 + (tid & 31);
    Bp[tid] = make_float2(Wih[g], b_ih[g] + b_hh[g]);
  }

  // ---- leader (m==0, wave 0): bounded purity check, publish verdict ----
  if (m == 0 && w == 0) {
    const unsigned ref = 0xA5000000u | xcc;
    unsigned v0 = 0, v1 = 0, v2 = 0, v3 = 0;
    int ok = 0;
    for (int it = 0; it < 16384; ++it) {
      DLOADX(v0, &vx[lane],       "sc0 sc1");
      DLOADX(v1, &vx[lane + 64],  "sc0 sc1");
      DLOADX(v2, &vx[lane + 128], "sc0 sc1");
      DLOADX(v3, &vx[lane + 192], "sc0 sc1");
      WAITV(0);
      if (__all((int)(((v0 & 0xFF000000u) == 0xA5000000u) &&
                      ((v1 & 0xFF000000u) == 0xA5000000u) &&
                      ((v2 & 0xFF000000u) == 0xA5000000u) &&
                      ((v3 & 0xFF000000u) == 0xA5000000u)))) { ok = 1; break; }
      __builtin_amdgcn_s_sleep(1);
    }
    unsigned verdict = 0;
    if (ok) {
      const bool mine = ((lane & 7) == n);
      int uni = __all((int)(!mine || (v0 == ref && v1 == ref && v2 == ref && v3 == ref)));
      int oth = __all((int)( mine || (v0 != ref && v1 != ref && v2 != ref && v3 != ref)));
      verdict = (uni && oth && (xcc < 8u)) ? 1u : 0u;
    }
    if (lane == 0)
      DSTOREX(&vdict[n], 0xB5000000u | (verdict << 8) | xcc, "sc0 sc1");
  }

  unsigned vd;
  for (;;) {
    DLOADX(vd, &vdict[n], "sc0 sc1");
    WAITV(0);
    if ((vd & 0xFF000000u) == 0xB5000000u) break;
    __builtin_amdgcn_s_sleep(2);
  }
  const int pure   = (int)((vd >> 8) & 1u);
  const unsigned x = vd & 0xFu;

  const int bb = bt * 64 + w * 16 + ln15;       // my batch row
  const size_t hoff  = (size_t)bb * 1024 + (size_t)q * 16;
  const size_t soff0 = (size_t)bb * 1024 + (size_t)(j0 + q4) * 2;
  const size_t soff1 = soff0 + 32;              // +16 cols
  const float* c_ptr = c_in + (size_t)bb * 256;

  float cc[2][4];
#pragma unroll
  for (int u = 0; u < 2; ++u)
#pragma unroll
    for (int r = 0; r < 4; ++r) cc[u][r] = 0.0f;

  // Sync group: 16 waves sharing (bt,w) across jt=0..15 — closed set.
  // Group id within XCD: gidx = bt*4 + w (8 groups).
  const int gidx = bt * 4 + w;
  char *curB, *nxtB;
  unsigned int *myflag, *cnt2, *cntM;
  const unsigned int *pf0;
  if (pure) {
    curB = hPure + (size_t)x * 262144; nxtB = curB + 131072;
    cnt2 = pcnt + x * 256 + gidx * 16;          // L2-resident counter line
    cntM = pcnt + x * 256 + 128 + gidx * 16;    // MALL-escrow counter line
    myflag = cnt2;                               // unused
    pf0    = cnt2;                               // unused
  } else {
    curB = hImp + (size_t)n * 131072; nxtB = curB + (size_t)NBR * 131072;
    unsigned int* flagB = iflags + n * 128;
    myflag = flagB + m * 4 + w;                  // per-wave flag
    pf0    = flagB + bt * 64 + lane;             // 64 same-batch-half wave flags
    cnt2 = myflag; cntM = myflag;                // unused
  }

  __syncthreads();   // Wlds + Bp ready; every wave has the verdict

  if (pure) {
    // scrub my 1/32 of region[x] to 0 (stale dirty lines live only in THIS L2)
    char* rp = hPure + (size_t)x * 262144 + (size_t)m * 8192;
    for (int i = tid; i < 1024; i += 256)
      QSTOREXO(rp + (size_t)i * 8, 0ull, "0", "sc0");
    // jt==0 blocks scrub their bt's 4 group counters:
    // L2 counter: dirty-0 in local L2. MALL counter: L2-0 first, then MALL-0.
    if (jt == 0 && lane == 0) {
      DSTOREX(cnt2, 0u, "sc0");
      DSTOREX(cntM, 0u, "sc0");
      WAITV(0);
      DSTOREX(cntM, 0u, "sc0 sc1");
    }
    WAITV(0);
    __syncthreads();
    if (tid == 0) DSTOREX(&ibar[x * 32 + m], 1u, "sc0 sc1");
    for (;;) {
      unsigned iv;
      DLOADX(iv, &ibar[x * 32 + (lane & 31)], "sc0 sc1");
      WAITV(0);
      if (__all((int)(iv >= 1u))) break;
      __builtin_amdgcn_s_sleep(2);
    }
    INVL1(); WAITV(0);
    STEP_LOOP("", 1)
  } else {
    STEP_LOOP("sc0 sc1", 0)
  }
}

// out[b,j] = sum_t (sum_n ys[t,n,b] * x[n,b,t]) * Wl[j,t] + bl[j]
__global__ __launch_bounds__(256) void finalize_k(
    const float* __restrict__ ys, const float* __restrict__ x,
    const float* __restrict__ Wl, const float* __restrict__ bl,
    float* __restrict__ out)
{
  int b = blockIdx.x;
  int tid = threadIdx.x;  // = t
  __shared__ float r[256];
  float acc = 0.f;
#pragma unroll
  for (int n = 0; n < NBR; ++n)
    acc += ys[tid * (NBR * BATCH) + n * BATCH + b] * x[(n * BATCH + b) * 256 + tid];
  r[tid] = acc;
  __syncthreads();
  int wv = tid >> 6, ln = tid & 63;
#pragma unroll
  for (int jj = 0; jj < 2; ++jj) {
    int j = wv * 2 + jj;
    float p = 0.f;
#pragma unroll
    for (int t2 = ln; t2 < 256; t2 += 64) p += r[t2] * Wl[j * 256 + t2];
#pragma unroll
    for (int s = 32; s > 0; s >>= 1) p += __shfl_down(p, s, 64);
    if (ln == 0) out[b * NBR + j] = p + bl[j];
  }
}

extern "C" void kernel_launch(void* const* d_in, const int* in_sizes, int n_in,
                              void* d_out, int out_size, void* d_ws, size_t ws_size,
                              hipStream_t stream) {
  const float* x    = (const float*)d_in[0];
  const float* c    = (const float*)d_in[1];
  const float* Wih  = (const float*)d_in[2];
  const float* Whh  = (const float*)d_in[3];
  const float* b_ih = (const float*)d_in[4];
  const float* b_hh = (const float*)d_in[5];
  // d_in[6] = hn0 (zeros; impure ping memset, pure regions scrubbed in-kernel)
  const float* Wl   = (const float*)d_in[7];
  const float* bl   = (const float*)d_in[8];
  float* out = (float*)d_out;

  char* ws = (char*)d_ws;
  char*  hImp  = ws;                                   // 2MB
  char*  hPure = ws + (2u << 20);                      // 2MB (8 x 256KB, XCD-indexed)
  float* ys    = (float*)(ws + (4u << 20));            // 1MB
  unsigned int* ctrl   = (unsigned int*)(ws + (5u << 20));
  unsigned int* iflags = ctrl;                         // 1024 u32
  unsigned int* pcnt   = ctrl + 1024;                  // 2048 u32 (8 x 256)
  unsigned int* vx     = ctrl + 3072;                  // 256 u32
  unsigned int* vdict  = ctrl + 3328;                  // 8 u32
  unsigned int* ibar   = ctrl + 3336;                  // 256 u32

  // ws re-poisoned (0xAA) before every timed launch: re-init every call.
  (void)hipMemsetAsync(hImp, 0, 1u << 20, stream);     // impure h(t=0) = 0
  (void)hipMemsetAsync(ctrl, 0, 3592u * sizeof(unsigned int), stream);

  lstm_main<<<256, 256, 0, stream>>>(c, Wih, Whh, b_ih, b_hh, hImp, hPure, ys,
                                     iflags, pcnt, vx, vdict, ibar);
  finalize_k<<<BATCH, 256, 0, stream>>>(ys, x, Wl, bl, out);
}

// Round 8
// 1038.938 us; speedup vs baseline: 1.4889x; 1.0525x over previous
//
#include <hip/hip_runtime.h>

// 8 independent LSTMs (HID=512, input=1 scalar/step) x T=256, batch 128, then a
// tiny (B,T)->(B,8) projection.
//
// Round 17: bisect r16's failure — r15 sync protocol VERBATIM + compute-side
// wins only (pb register hoist, acc bias seeding, ys off the publish path).
//  r16 post-mortem (FAILED absmax 4.2e-2): bundled {escrow removal + 4-way
//  split counters} with {pb hoist + acc seed + ys move}. Split-counter
//  induction is provably sound; prime suspect is the escrow removal: vmcnt-ack
//  for plain stores may be "accepted" not "L2-visible", and h lines vs counter
//  line hit DIFFERENT TCC channels -> publish can outrun h stores. r15's
//  escrow ack (~700cy, drained by first poll WAITV(0)) masked that window;
//  r16's fast single-add detect exposed it.
//  r17 = r15 sync/scrub/poll byte-identical (single group counter, plain L2
//  add + sc1 escrow add, lane0 sc0 umax poll, 256-spin escalation, sleep(1)),
//  plus ONLY:
//   - {Wih, bias} hoisted from LDS Bp into 64 VGPRs (pb[32]) once;
//   - acc seeded with bias via MFMA C-input (kills 32 zero-movs + 32 adds);
//   - ys store moved off the group-critical path (after publish in pure mode).

#define NBR   8
#define BATCH 128
#define HIDN  512
#define TLEN  256

typedef __attribute__((ext_vector_type(8))) short bf16x8;
typedef __attribute__((ext_vector_type(4))) float f32x4;

__device__ __forceinline__ unsigned short bf16_rne(float f) {
  unsigned int u = __float_as_uint(f);
  u += 0x7FFFu + ((u >> 16) & 1u);
  return (unsigned short)(u >> 16);
}

__device__ __forceinline__ float sigm(float x) {
  return __builtin_amdgcn_rcpf(1.0f + __expf(-x));
}
__device__ __forceinline__ float tanh_(float x) {
  float ax = fabsf(x);
  float e  = __expf(-2.0f * ax);
  float t  = (1.0f - e) * __builtin_amdgcn_rcpf(1.0f + e);
  return copysignf(t, x);
}

#define HLOADX(d, p, OFF, SC) \
  asm volatile("global_load_dwordx4 %0, %1, off offset:" OFF " " SC \
               : "=v"(d) : "v"(p))
#define DLOADX(d, p, SC) \
  asm volatile("global_load_dword %0, %1, off " SC : "=v"(d) : "v"(p))
#define DLOADF(d, p, SC) \
  asm volatile("global_load_dword %0, %1, off " SC : "=v"(d) : "v"(p))
#define QSTOREX(p, v, SC) \
  asm volatile("global_store_dwordx2 %0, %1, off " SC \
               :: "v"(p), "v"(v) : "memory")
#define QSTOREXO(p, v, OFF, SC) \
  asm volatile("global_store_dwordx2 %0, %1, off offset:" OFF " " SC \
               :: "v"(p), "v"(v) : "memory")
#define DSTOREX(p, v, SC) \
  asm volatile("global_store_dword %0, %1, off " SC \
               :: "v"(p), "v"(v) : "memory")
#define WAITV(N) asm volatile("s_waitcnt vmcnt(" #N ")" ::: "memory")
#define INVL1() asm volatile("buffer_inv sc0" ::: "memory")
#define SCHEDB() __builtin_amdgcn_sched_barrier(0)
// L2-executed atomics: cannot be served stale by L1. sc0 on the RET form is
// required (return-old); plain NR form executes at L2, sc1 form at MALL.
#define AADD_NR(p, v, SC) \
  asm volatile("global_atomic_add %0, %1, off " SC :: "v"(p), "v"(v) : "memory")
#define AUMAX_RET(d, p, v, SC) \
  asm volatile("global_atomic_umax %0, %1, %2, off " SC \
               : "=v"(d) : "v"(p), "v"(v) : "memory")

// 16 x 16B: row bb, bytes [q*16 + j*64], j = 0..15 (4 chunks of 4 ksteps).
#define LOAD_H(SC) do {                         \
    HLOADX(hvv[0][0], pc, "0",   SC);           \
    HLOADX(hvv[0][1], pc, "64",  SC);           \
    HLOADX(hvv[0][2], pc, "128", SC);           \
    HLOADX(hvv[0][3], pc, "192", SC);           \
    HLOADX(hvv[1][0], pc, "256", SC);           \
    HLOADX(hvv[1][1], pc, "320", SC);           \
    HLOADX(hvv[1][2], pc, "384", SC);           \
    HLOADX(hvv[1][3], pc, "448", SC);           \
    HLOADX(hvv[2][0], pc, "512", SC);           \
    HLOADX(hvv[2][1], pc, "576", SC);           \
    HLOADX(hvv[2][2], pc, "640", SC);           \
    HLOADX(hvv[2][3], pc, "704", SC);           \
    HLOADX(hvv[3][0], pc, "768", SC);           \
    HLOADX(hvv[3][1], pc, "832", SC);           \
    HLOADX(hvv[3][2], pc, "896", SC);           \
    HLOADX(hvv[3][3], pc, "960", SC);           \
  } while (0)

// 8 tiles tt = gate*2 + u (u = col-16-half); acc[tt] over K chunks. W from
// frag-major LDS: index tt*1024 + ks*64 + wb (wb = q*16+ln15) -> each read is
// 64 consecutive uint4 = conflict-free.
#define MFMA_CHUNK(C) do {                                                    \
    _Pragma("unroll")                                                         \
    for (int k4 = 0; k4 < 4; ++k4) {                                          \
      bf16x8 hfrag = __builtin_bit_cast(bf16x8, hvv[C][k4]);                  \
      _Pragma("unroll")                                                       \
      for (int tt = 0; tt < 8; ++tt) {                                        \
        bf16x8 wf = __builtin_bit_cast(bf16x8,                                \
            Wlds[tt * 1024 + (4 * (C) + k4) * 64 + wb]);                      \
        acc[tt] = __builtin_amdgcn_mfma_f32_16x16x32_bf16(                    \
            wf, hfrag, acc[tt], 0, 0, 0);                                     \
      }                                                                       \
    }                                                                         \
  } while (0)

// FM==1: pure (plain h exchange in local L2, per-group counter sync,
// sc1 escrow + escalation — r15-proven). FM==0: MALL protocol, per-wave flags.
#define STEP_LOOP(SC, FM)                                                     \
  for (int t = 0; t < TLEN; ++t) {                                            \
    f32x4 acc[8];                                                             \
    _Pragma("unroll")                                                         \
    for (int tt = 0; tt < 8; ++tt)                                            \
      acc[tt] = (f32x4){pb[tt * 4 + 0].y, pb[tt * 4 + 1].y,                   \
                        pb[tt * 4 + 2].y, pb[tt * 4 + 3].y};                  \
    const char* pc = curB + hoff;                                             \
    uint4 hvv[4][4];                                                          \
    float cv;                                                                 \
    DLOADF(cv, c_ptr + t, "");                                                \
    LOAD_H(SC);                                                               \
    WAITV(12); SCHEDB(); MFMA_CHUNK(0);                                       \
    WAITV(8);  SCHEDB(); MFMA_CHUNK(1);                                       \
    WAITV(4);  SCHEDB(); MFMA_CHUNK(2);                                       \
    WAITV(0);  SCHEDB(); MFMA_CHUNK(3);                                       \
    float hv3 = 0.f;                                                          \
    _Pragma("unroll")                                                         \
    for (int u = 0; u < 2; ++u) {                                             \
      unsigned lo = 0, hi = 0;                                                \
      _Pragma("unroll")                                                       \
      for (int r = 0; r < 4; ++r) {                                           \
        float gi = acc[0 + u][r] + pb[(0 + u) * 4 + r].x * cv;                \
        float gf = acc[2 + u][r] + pb[(2 + u) * 4 + r].x * cv;                \
        float gg = acc[4 + u][r] + pb[(4 + u) * 4 + r].x * cv;                \
        float go = acc[6 + u][r] + pb[(6 + u) * 4 + r].x * cv;                \
        float ncc = sigm(gf) * cc[u][r] + sigm(gi) * tanh_(gg);               \
        cc[u][r] = ncc;                                                       \
        float hval = sigm(go) * tanh_(ncc);                                   \
        unsigned hb = bf16_rne(hval);                                         \
        if (r == 0) lo = hb;                                                  \
        if (r == 1) lo |= hb << 16;                                           \
        if (r == 2) hi = hb;                                                  \
        if (r == 3) hi |= hb << 16;                                           \
        if (u == 1 && r == 3) hv3 = hval;                                     \
      }                                                                       \
      unsigned long long pack =                                               \
          (unsigned long long)lo | ((unsigned long long)hi << 32);            \
      QSTOREX(nxtB + (u ? soff1 : soff0), pack, SC);                          \
    }                                                                         \
    if (t == TLEN - 1) {                                                      \
      if (jt == 15 && q == 3)                                                 \
        ys[t * (NBR * BATCH) + n * BATCH + bb] = hv3;                         \
      break;                                                                  \
    }                                                                         \
    WAITV(0);                      /* my h stores acked */                    \
    const unsigned tgt = (unsigned)(t + 1);                                   \
    if (FM) {                                                                 \
      if (lane == 0) { AADD_NR(cnt2, one, "");                                \
                       AADD_NR(cntM, one, "sc1"); }                           \
      INVL1();                     /* atomics bypass L1; no refill before h */\
      if (jt == 15 && q == 3)                                                 \
        ys[t * (NBR * BATCH) + n * BATCH + bb] = hv3;                         \
      const unsigned tgt16 = tgt << 4;                                        \
      int spins = 0;                                                          \
      for (;;) {                                                              \
        unsigned fv = 0xFFFFFFFFu;                                            \
        if (lane == 0) {                                                      \
          if (spins < 256) { AUMAX_RET(fv, cnt2, 0u, "sc0"); }                \
          else             { AUMAX_RET(fv, cntM, 0u, "sc0 sc1"); }            \
        }                                                                     \
        WAITV(0); SCHEDB();        /* also drains the buffer_inv */           \
        if (__all((int)(fv >= tgt16))) break;                                 \
        ++spins; __builtin_amdgcn_s_sleep(1);                                 \
      }                                                                       \
    } else {                                                                  \
      if (jt == 15 && q == 3)                                                 \
        ys[t * (NBR * BATCH) + n * BATCH + bb] = hv3;                         \
      if (lane == 0) DSTOREX(myflag, tgt, "sc0 sc1");                         \
      for (;;) {                                                              \
        unsigned f0v;                                                         \
        DLOADX(f0v, pf0, "sc0 sc1");                                          \
        WAITV(0); SCHEDB();                                                   \
        if (__all((int)(f0v >= tgt))) break;                                  \
        __builtin_amdgcn_s_sleep(1);                                          \
      }                                                                       \
    }                                                                         \
    char* tsw = curB; curB = nxtB; nxtB = tsw;                                \
  }

__global__ __launch_bounds__(256, 1) void lstm_main(
    const float* __restrict__ c_in,   // (128,256)
    const float* __restrict__ Wih,    // (8,2048)
    const float* __restrict__ Whh,    // (8,2048,512)
    const float* __restrict__ b_ih,   // (8,2048)
    const float* __restrict__ b_hh,   // (8,2048)
    char* __restrict__ hImp,          // 2MB impure ping+pong, pre-zeroed ping
    char* __restrict__ hPure,         // 2MB: 8 XCD regions x (128KB ping + 128KB pong)
    float* __restrict__ ys,           // (256,8,128)
    unsigned int* __restrict__ iflags,// 8x128 impure per-wave flags, pre-zeroed
    unsigned int* __restrict__ pcnt,  // 8 XCD x {8 L2-cnt, 8 MALL-cnt} x 16 u32
    unsigned int* __restrict__ vx,    // 256 tagged XCC slots, pre-zeroed
    unsigned int* __restrict__ vdict, // 8 verdicts, pre-zeroed
    unsigned int* __restrict__ ibar)  // 8x32 init-barrier slots, pre-zeroed
{
  // Frag-major W: slot = tile*1024 + ks*64 + q*16 + ln15  (tile = gate*2 + u).
  // Each ds_read_b128 (fixed tile,ks) touches 64 CONSECUTIVE uint4 slots.
  __shared__ uint4 Wlds[8192];  // 128KB
  __shared__ float2 Bp[128];    // {Wih, b_ih+b_hh} per slice gate-row

  const int tid  = threadIdx.x;
  const int lane = tid & 63;
  const int w    = tid >> 6;
  const int ln15 = lane & 15;
  const int q    = lane >> 4;
  const int q4   = q * 4;
  const int n    = blockIdx.x & 7;    // branch
  const int m    = blockIdx.x >> 3;   // 0..31
  const int jt   = m & 15;            // hidden-col tile (32 cols)
  const int bt   = m >> 4;            // batch half (64 rows)
  const int j0   = jt << 5;
  const int wb   = q * 16 + ln15;     // frag-major LDS read base (uint4)
  const unsigned one = 1u;

  unsigned xcc_raw;
  asm volatile("s_getreg_b32 %0, hwreg(HW_REG_XCC_ID)" : "=s"(xcc_raw));
  const unsigned xcc = xcc_raw & 0xFu;
  if (tid == 0) DSTOREX(&vx[blockIdx.x], 0xA5000000u | xcc, "sc0 sc1");

  // ---- stage Whh slice -> LDS bf16, frag-major, dest-linear (once) ----
  for (int idx = tid; idx < 8192; idx += 256) {
    int ln   = idx & 15;          // wcol within 16-col tile
    int q_   = (idx >> 4) & 3;    // k quarter (8 floats)
    int ks_  = (idx >> 6) & 15;   // kstep (32 floats)
    int tile = idx >> 10;         // 0..7 = gate*2 + u
    int g_   = tile >> 1;
    int uu   = tile & 1;
    const float* src = Whh +
        (size_t)(n * 2048 + g_ * 512 + j0 + uu * 16 + ln) * 512 + ks_ * 32 + q_ * 8;
    float4 f0 = *(const float4*)(src);
    float4 f1 = *(const float4*)(src + 4);
    uint4 v;
    v.x = (unsigned)bf16_rne(f0.x) | ((unsigned)bf16_rne(f0.y) << 16);
    v.y = (unsigned)bf16_rne(f0.z) | ((unsigned)bf16_rne(f0.w) << 16);
    v.z = (unsigned)bf16_rne(f1.x) | ((unsigned)bf16_rne(f1.y) << 16);
    v.w = (unsigned)bf16_rne(f1.z) | ((unsigned)bf16_rne(f1.w) << 16);
    Wlds[idx] = v;
  }
  if (tid < 128) {
    int g = n * 2048 + (tid >> 5) * 512 + j0 + (tid & 31);
    Bp[tid] = make_float2(Wih[g], b_ih[g] + b_hh[g]);
  }

  // ---- leader (m==0, wave 0): bounded purity check, publish verdict ----
  if (m == 0 && w == 0) {
    const unsigned ref = 0xA5000000u | xcc;
    unsigned v0 = 0, v1 = 0, v2 = 0, v3 = 0;
    int ok = 0;
    for (int it = 0; it < 16384; ++it) {
      DLOADX(v0, &vx[lane],       "sc0 sc1");
      DLOADX(v1, &vx[lane + 64],  "sc0 sc1");
      DLOADX(v2, &vx[lane + 128], "sc0 sc1");
      DLOADX(v3, &vx[lane + 192], "sc0 sc1");
      WAITV(0);
      if (__all((int)(((v0 & 0xFF000000u) == 0xA5000000u) &&
                      ((v1 & 0xFF000000u) == 0xA5000000u) &&
                      ((v2 & 0xFF000000u) == 0xA5000000u) &&
                      ((v3 & 0xFF000000u) == 0xA5000000u)))) { ok = 1; break; }
      __builtin_amdgcn_s_sleep(1);
    }
    unsigned verdict = 0;
    if (ok) {
      const bool mine = ((lane & 7) == n);
      int uni = __all((int)(!mine || (v0 == ref && v1 == ref && v2 == ref && v3 == ref)));
      int oth = __all((int)( mine || (v0 != ref && v1 != ref && v2 != ref && v3 != ref)));
      verdict = (uni && oth && (xcc < 8u)) ? 1u : 0u;
    }
    if (lane == 0)
      DSTOREX(&vdict[n], 0xB5000000u | (verdict << 8) | xcc, "sc0 sc1");
  }

  unsigned vd;
  for (;;) {
    DLOADX(vd, &vdict[n], "sc0 sc1");
    WAITV(0);
    if ((vd & 0xFF000000u) == 0xB5000000u) break;
    __builtin_amdgcn_s_sleep(2);
  }
  const int pure   = (int)((vd >> 8) & 1u);
  const unsigned x = vd & 0xFu;

  const int bb = bt * 64 + w * 16 + ln15;       // my batch row
  const size_t hoff  = (size_t)bb * 1024 + (size_t)q * 16;
  const size_t soff0 = (size_t)bb * 1024 + (size_t)(j0 + q4) * 2;
  const size_t soff1 = soff0 + 32;              // +16 cols
  const float* c_ptr = c_in + (size_t)bb * 256;

  float cc[2][4];
#pragma unroll
  for (int u = 0; u < 2; ++u)
#pragma unroll
    for (int r = 0; r < 4; ++r) cc[u][r] = 0.0f;

  // Sync group: 16 waves sharing (bt,w) across jt=0..15 — closed set.
  // Group id within XCD: gidx = bt*4 + w (8 groups).
  const int gidx = bt * 4 + w;
  char *curB, *nxtB;
  unsigned int *myflag, *cnt2, *cntM;
  const unsigned int *pf0;
  if (pure) {
    curB = hPure + (size_t)x * 262144; nxtB = curB + 131072;
    cnt2 = pcnt + x * 256 + gidx * 16;          // L2-resident counter line
    cntM = pcnt + x * 256 + 128 + gidx * 16;    // MALL-escrow counter line
    myflag = cnt2;                               // unused
    pf0    = cnt2;                               // unused
  } else {
    curB = hImp + (size_t)n * 131072; nxtB = curB + (size_t)NBR * 131072;
    unsigned int* flagB = iflags + n * 128;
    myflag = flagB + m * 4 + w;                  // per-wave flag
    pf0    = flagB + bt * 64 + lane;             // 64 same-batch-half wave flags
    cnt2 = myflag; cntM = myflag;                // unused
  }

  __syncthreads();   // Wlds + Bp ready; every wave has the verdict

  // Hoist {Wih, bias} for my 32 output elems into registers (loop-invariant).
  float2 pb[32];
#pragma unroll
  for (int g_ = 0; g_ < 4; ++g_)
#pragma unroll
    for (int uu = 0; uu < 2; ++uu)
#pragma unroll
      for (int r = 0; r < 4; ++r)
        pb[(g_ * 2 + uu) * 4 + r] = Bp[g_ * 32 + uu * 16 + q4 + r];

  if (pure) {
    // scrub my 1/32 of region[x] to 0 (stale dirty lines live only in THIS L2)
    char* rp = hPure + (size_t)x * 262144 + (size_t)m * 8192;
    for (int i = tid; i < 1024; i += 256)
      QSTOREXO(rp + (size_t)i * 8, 0ull, "0", "sc0");
    // jt==0 blocks scrub their bt's 4 group counters:
    // L2 counter: dirty-0 in local L2. MALL counter: L2-0 first, then MALL-0.
    if (jt == 0 && lane == 0) {
      DSTOREX(cnt2, 0u, "sc0");
      DSTOREX(cntM, 0u, "sc0");
      WAITV(0);
      DSTOREX(cntM, 0u, "sc0 sc1");
    }
    WAITV(0);
    __syncthreads();
    if (tid == 0) DSTOREX(&ibar[x * 32 + m], 1u, "sc0 sc1");
    for (;;) {
      unsigned iv;
      DLOADX(iv, &ibar[x * 32 + (lane & 31)], "sc0 sc1");
      WAITV(0);
      if (__all((int)(iv >= 1u))) break;
      __builtin_amdgcn_s_sleep(2);
    }
    INVL1(); WAITV(0);
    STEP_LOOP("", 1)
  } else {
    STEP_LOOP("sc0 sc1", 0)
  }
}

// out[b,j] = sum_t (sum_n ys[t,n,b] * x[n,b,t]) * Wl[j,t] + bl[j]
__global__ __launch_bounds__(256) void finalize_k(
    const float* __restrict__ ys, const float* __restrict__ x,
    const float* __restrict__ Wl, const float* __restrict__ bl,
    float* __restrict__ out)
{
  int b = blockIdx.x;
  int tid = threadIdx.x;  // = t
  __shared__ float r[256];
  float acc = 0.f;
#pragma unroll
  for (int n = 0; n < NBR; ++n)
    acc += ys[tid * (NBR * BATCH) + n * BATCH + b] * x[(n * BATCH + b) * 256 + tid];
  r[tid] = acc;
  __syncthreads();
  int wv = tid >> 6, ln = tid & 63;
#pragma unroll
  for (int jj = 0; jj < 2; ++jj) {
    int j = wv * 2 + jj;
    float p = 0.f;
#pragma unroll
    for (int t2 = ln; t2 < 256; t2 += 64) p += r[t2] * Wl[j * 256 + t2];
#pragma unroll
    for (int s = 32; s > 0; s >>= 1) p += __shfl_down(p, s, 64);
    if (ln == 0) out[b * NBR + j] = p + bl[j];
  }
}

extern "C" void kernel_launch(void* const* d_in, const int* in_sizes, int n_in,
                              void* d_out, int out_size, void* d_ws, size_t ws_size,
                              hipStream_t stream) {
  const float* x    = (const float*)d_in[0];
  const float* c    = (const float*)d_in[1];
  const float* Wih  = (const float*)d_in[2];
  const float* Whh  = (const float*)d_in[3];
  const float* b_ih = (const float*)d_in[4];
  const float* b_hh = (const float*)d_in[5];
  // d_in[6] = hn0 (zeros; impure ping memset, pure regions scrubbed in-kernel)
  const float* Wl   = (const float*)d_in[7];
  const float* bl   = (const float*)d_in[8];
  float* out = (float*)d_out;

  char* ws = (char*)d_ws;
  char*  hImp  = ws;                                   // 2MB
  char*  hPure = ws + (2u << 20);                      // 2MB (8 x 256KB, XCD-indexed)
  float* ys    = (float*)(ws + (4u << 20));            // 1MB
  unsigned int* ctrl   = (unsigned int*)(ws + (5u << 20));
  unsigned int* iflags = ctrl;                         // 1024 u32
  unsigned int* pcnt   = ctrl + 1024;                  // 2048 u32 (8 x 256)
  unsigned int* vx     = ctrl + 3072;                  // 256 u32
  unsigned int* vdict  = ctrl + 3328;                  // 8 u32
  unsigned int* ibar   = ctrl + 3336;                  // 256 u32

  // ws re-poisoned (0xAA) before every timed launch: re-init every call.
  (void)hipMemsetAsync(hImp, 0, 1u << 20, stream);     // impure h(t=0) = 0
  (void)hipMemsetAsync(ctrl, 0, 3592u * sizeof(unsigned int), stream);

  lstm_main<<<256, 256, 0, stream>>>(c, Wih, Whh, b_ih, b_hh, hImp, hPure, ys,
                                     iflags, pcnt, vx, vdict, ibar);
  finalize_k<<<BATCH, 256, 0, stream>>>(ys, x, Wl, bl, out);
}